// Round 15
// baseline (82.775 us; speedup 1.0000x reference)
//
#include <hip/hip_runtime.h>

#define NSTEPS 24
#define HALFW  2048

typedef float float2v __attribute__((ext_vector_type(2)));

// R10 swizzle (bijective triangular XOR) — 0 conflicts measured with the
// R14 split-buffer TRANS.
#define SWZ(q) ((q) ^ (((q) >> 4) & 31) ^ (((q) >> 3) & 8))

// Phase maps for 512 threads x 8 elems (R10-verified): lane bits stay in
// q[3:0] at load (QA) and store (QD) phases => dense coalescing.
#define QA(e) (((e) << 9) | t)                                  // e in 11..9
#define QB(e) ((((t) >> 6) << 9) | ((e) << 6) | ((t) & 63))     // e in 8..6
#define QC(e) ((((t) >> 3) << 6) | ((e) << 3) | ((t) & 7))      // e in 5..3
#define QD(e) (((t) << 3) | (e))                                // e in 2..0

#define SB() __builtin_amdgcn_sched_barrier(0)

// cs-table: tab[(d*2048 + t*4 + p)*2] = {cos,sin}. R10/R11-verified index
// derivation (PERM = ror12; step d butterflies bit 11-(d%12); l =
// rotl12(q0, d%12) & 0x7FF); payload back to (c,s) pairs (R0-proven size:
// 24*2048*2*4 = 393,216 B <= ws). Removes 192 trans-pipe instrs + splats
// from every step's dependent chain at +8 VGPR (52->~60, same 4-wave tier).
__global__ void build_tab_kernel(const float* __restrict__ params,
                                 float* __restrict__ tab) {
    int idx = blockIdx.x * 256 + threadIdx.x;
    if (idx >= NSTEPS * HALFW) return;
    int d  = idx >> 11;
    int j  = idx & (HALFW - 1);
    int t  = j >> 2;              // 0..511
    int p  = j & 3;               // pair index (2 bits)
    int ph = d / 3;               // phase 0..7, map = ph & 3
    int k  = 2 - (d % 3);         // butterfly bit within the 3-bit group
    int e0 = ((p >> k) << (k + 1)) | (p & ((1 << k) - 1)); // insert 0 at bit k
    int q0;
    switch (ph & 3) {
        case 0:  q0 = (e0 << 9) | t; break;
        case 1:  q0 = ((t >> 6) << 9) | (e0 << 6) | (t & 63); break;
        case 2:  q0 = ((t >> 3) << 6) | (e0 << 3) | (t & 7); break;
        default: q0 = (t << 3) | e0; break;
    }
    int dd = d % 12;
    int l = ((q0 << dd) | (q0 >> (12 - dd))) & 0xFFF;       // rotl12(q0, dd)
    l &= 0x7FF;
    float theta = params[l * NSTEPS + d];   // params (2048, 24) row-major
    float s, c;
    sincosf(theta, &s, &c);
    tab[2 * idx]     = c;
    tab[2 * idx + 1] = s;
}

// 8-float cs load (2x dwordx4, SROA-safe scalar unpack).
__device__ __forceinline__ void ldcs8(float (&dst)[8], const float* __restrict__ p) {
    const float4* ap = (const float4*)p;
    float4 q0 = ap[0], q1 = ap[1];
    dst[0] = q0.x; dst[1] = q0.y; dst[2] = q0.z; dst[3] = q0.w;
    dst[4] = q1.x; dst[5] = q1.y; dst[6] = q1.z; dst[7] = q1.w;
}

// Packed butterfly on bit KK applied to BOTH pipelines (4 rows) with table
// (c,s) — chain is load -> pk-fma, no trans-pipe. 8 independent chains/p.
template<int KK>
__device__ __forceinline__ void bfly2(float2v (&ra)[8], float2v (&rb)[8],
                                      const float (&cs)[8]) {
    #pragma unroll
    for (int p = 0; p < 4; ++p) {
        const int e0 = ((p >> KK) << (KK + 1)) | (p & ((1 << KK) - 1));
        const int e1 = e0 | (1 << KK);
        const float c = cs[2 * p];
        const float s = cs[2 * p + 1];
        const float2v cv = {c, c};
        const float2v sv = {s, s};
        const float2v a0 = ra[e0], a1 = ra[e1];
        ra[e0] = __builtin_elementwise_fma(cv, a0, sv * a1);
        ra[e1] = __builtin_elementwise_fma(cv, a1, -(sv * a0));
        const float2v b0 = rb[e0], b1 = rb[e1];
        rb[e0] = __builtin_elementwise_fma(cv, b0, sv * b1);
        rb[e1] = __builtin_elementwise_fma(cv, b1, -(sv * b0));
    }
}

// 3 butterfly steps (one phase); cs dbuf ce/co, distance-2 prefetch pinned
// after each last use (R11/R14 record pattern; R13 proved distance-1
// regresses). Step stride in the cs table: 2048 float2 = 4096 floats.
template<int BASE>
__device__ __forceinline__ void group3(float2v (&ra)[8], float2v (&rb)[8],
        float (&ce)[8], float (&co)[8], const float* __restrict__ tb) {
    if constexpr ((BASE & 1) == 0) {
        bfly2<2>(ra, rb, ce);
        if constexpr (BASE + 2 < NSTEPS) { ldcs8(ce, tb + (BASE + 2) * 4096); SB(); }
        bfly2<1>(ra, rb, co);
        if constexpr (BASE + 3 < NSTEPS) { ldcs8(co, tb + (BASE + 3) * 4096); SB(); }
        bfly2<0>(ra, rb, ce);
        if constexpr (BASE + 4 < NSTEPS) { ldcs8(ce, tb + (BASE + 4) * 4096); SB(); }
    } else {
        bfly2<2>(ra, rb, co);
        if constexpr (BASE + 2 < NSTEPS) { ldcs8(co, tb + (BASE + 2) * 4096); SB(); }
        bfly2<1>(ra, rb, ce);
        if constexpr (BASE + 3 < NSTEPS) { ldcs8(ce, tb + (BASE + 3) * 4096); SB(); }
        bfly2<0>(ra, rb, co);
        if constexpr (BASE + 4 < NSTEPS) { ldcs8(co, tb + (BASE + 4) * 4096); SB(); }
    }
}

// R14 split-buffer transpose: ONE barrier per transition, 0 conflicts
// measured. Sync elision between read and next write: R9 same-thread
// bijection (QS_{k+1} = QDm_k).
#define TRANS(QS, QDm) do {                                                   \
    _Pragma("unroll")                                                         \
    for (int e = 0; e < 8; ++e) {                                             \
        const int a = SWZ(QS(e));                                             \
        ldsA[a] = rpA[e];                                                     \
        ldsB[a] = rpB[e];                                                     \
    }                                                                         \
    __syncthreads();                                                          \
    _Pragma("unroll")                                                         \
    for (int e = 0; e < 8; ++e) {                                             \
        const int a = SWZ(QDm(e));                                            \
        rpA[e] = ldsA[a];                                                     \
        rpB[e] = ldsB[a];                                                     \
    }                                                                         \
} while (0)

// (512,4): cap VGPR at 64 — exactly the 4-waves/SIMD tier we already sit
// in. Essential state ~58 (rp 32 + cs 16 + misc), headroom ~6: mild remat
// pressure only, NOT an R12-style sub-essential squeeze. Watch FETCH/WRITE
// for spill signature regardless.
__global__ __launch_bounds__(512, 4)
void bfly_kernel(const float* __restrict__ X,
                 const float* __restrict__ tab,
                 float* __restrict__ Y) {
    __shared__ float2v ldsA[4096];     // 32 KiB, pipeline A (rows 0,1)
    __shared__ float2v ldsB[4096];     // 32 KiB, pipeline B (rows 2,3)
    const int t = threadIdx.x;
    const size_t row0 = (size_t)blockIdx.x * 4;

    const float* tb = tab + t * 8;     // t*4 float2 = t*8 floats
    float ce[8], co[8];
    ldcs8(ce, tb + 0 * 4096);
    ldcs8(co, tb + 1 * 4096);
    SB();

    float2v rpA[8], rpB[8];            // A: rows 0,1  B: rows 2,3
    {
        const float* x0 = X + row0 * 4096;
        const float* x1 = x0 + 4096;
        const float* x2 = x0 + 8192;
        const float* x3 = x0 + 12288;
        #pragma unroll
        for (int e = 0; e < 8; ++e) {
            const int a = QA(e);   // consecutive lanes, consecutive addresses
            rpA[e].x = x0[a];
            rpA[e].y = x1[a];
            rpB[e].x = x2[a];
            rpB[e].y = x3[a];
        }
    }

    group3<0 >(rpA, rpB, ce, co, tb);   TRANS(QA, QB);   // steps 0..2   bits 11..9
    group3<3 >(rpA, rpB, ce, co, tb);   TRANS(QB, QC);   // steps 3..5   bits 8..6
    group3<6 >(rpA, rpB, ce, co, tb);   TRANS(QC, QD);   // steps 6..8   bits 5..3
    group3<9 >(rpA, rpB, ce, co, tb);   TRANS(QD, QA);   // steps 9..11  bits 2..0
    group3<12>(rpA, rpB, ce, co, tb);   TRANS(QA, QB);   // steps 12..14 bits 11..9
    group3<15>(rpA, rpB, ce, co, tb);   TRANS(QB, QC);   // steps 15..17 bits 8..6
    group3<18>(rpA, rpB, ce, co, tb);   TRANS(QC, QD);   // steps 18..20 bits 5..3
    group3<21>(rpA, rpB, ce, co, tb);                    // steps 21..23 bits 2..0

    // QD layout: thread t holds 8 consecutive columns at t*8, 4 rows.
    {
        float* y0 = Y + row0 * 4096 + (t << 3);
        float* y1 = y0 + 4096;
        float* y2 = y0 + 8192;
        float* y3 = y0 + 12288;
        float4 v;
        v.x = rpA[0].x; v.y = rpA[1].x; v.z = rpA[2].x; v.w = rpA[3].x;
        *(float4*)&y0[0] = v;
        v.x = rpA[4].x; v.y = rpA[5].x; v.z = rpA[6].x; v.w = rpA[7].x;
        *(float4*)&y0[4] = v;
        v.x = rpA[0].y; v.y = rpA[1].y; v.z = rpA[2].y; v.w = rpA[3].y;
        *(float4*)&y1[0] = v;
        v.x = rpA[4].y; v.y = rpA[5].y; v.z = rpA[6].y; v.w = rpA[7].y;
        *(float4*)&y1[4] = v;
        v.x = rpB[0].x; v.y = rpB[1].x; v.z = rpB[2].x; v.w = rpB[3].x;
        *(float4*)&y2[0] = v;
        v.x = rpB[4].x; v.y = rpB[5].x; v.z = rpB[6].x; v.w = rpB[7].x;
        *(float4*)&y2[4] = v;
        v.x = rpB[0].y; v.y = rpB[1].y; v.z = rpB[2].y; v.w = rpB[3].y;
        *(float4*)&y3[0] = v;
        v.x = rpB[4].y; v.y = rpB[5].y; v.z = rpB[6].y; v.w = rpB[7].y;
        *(float4*)&y3[4] = v;
    }
}

extern "C" void kernel_launch(void* const* d_in, const int* in_sizes, int n_in,
                              void* d_out, int out_size, void* d_ws, size_t ws_size,
                              hipStream_t stream) {
    const float* X      = (const float*)d_in[0];
    const float* params = (const float*)d_in[1];
    float* out = (float*)d_out;
    float* tab = (float*)d_ws;   // 24*2048*2*4 = 393,216 bytes (cs pairs)

    hipLaunchKernelGGL(build_tab_kernel,
                       dim3((NSTEPS * HALFW + 255) / 256), dim3(256), 0, stream,
                       params, tab);
    hipLaunchKernelGGL(bfly_kernel,
                       dim3(8192 / 4), dim3(512), 0, stream,
                       X, tab, out);
}